// Round 1
// baseline (100.321 us; speedup 1.0000x reference)
//
#include <hip/hip_runtime.h>
#include <math.h>

#define NROWS 32768
#define DDIM  1024
#define NEXP  64
#define BM    64
#define BK    64
#define LPAD  (BK + 4)   // 68-float row stride -> conflict-free row-strided reads
#define EPSF  1e-9f

// ---------------------------------------------------------------------------
// Fused router: GEMM (x @ gate_w^T) + softmax + top-2 + aux-prob accumulation
// grid = 512 blocks (one per 64 rows), block = 256 threads (4 waves).
// Wave-level split-K: wave w accumulates kk in [w*16, w*16+16) of each BK=64
// chunk; partials tree-reduced through LDS at the end (also improves fp32
// summation accuracy ~2.5x vs a single chain -> fewer top-k index flips).
// ---------------------------------------------------------------------------
__global__ __launch_bounds__(256, 2) void moe_router_kernel(
    const float* __restrict__ x, const float* __restrict__ gw,
    float* __restrict__ out, float* __restrict__ meanacc)
{
    __shared__ float xs[BM][LPAD];
    __shared__ float wsh[NEXP][LPAD];

    const int t    = threadIdx.x;
    const int wave = t >> 6;
    const int lane = t & 63;
    const int tr   = lane >> 3;   // row group 0..7   (rows  tr + 8*i)
    const int tc   = lane & 7;    // expert group 0..7 (experts tc + 8*j)
    const int row0 = blockIdx.x * BM;

    float acc[8][8];
    #pragma unroll
    for (int i = 0; i < 8; ++i)
        #pragma unroll
        for (int j = 0; j < 8; ++j) acc[i][j] = 0.0f;

    for (int k0 = 0; k0 < DDIM; k0 += BK) {
        __syncthreads();
        // ---- stage x-tile [64][64] and w-tile [64][64] (coalesced f4 loads)
        #pragma unroll
        for (int s = 0; s < 4; ++s) {
            int g = (s * 256 + t) * 4;      // flat float index in tile
            int r = g >> 6;
            int c = g & 63;
            float4 xv = *reinterpret_cast<const float4*>(
                x + (size_t)(row0 + r) * DDIM + k0 + c);
            float4 wv = *reinterpret_cast<const float4*>(
                gw + (size_t)r * DDIM + k0 + c);
            *reinterpret_cast<float4*>(&xs[r][c])  = xv;
            *reinterpret_cast<float4*>(&wsh[r][c]) = wv;
        }
        __syncthreads();
        // ---- compute: this wave's K-slice (16 of the 64 kk)
        #pragma unroll
        for (int s = 0; s < 4; ++s) {
            const int c = (wave * 4 + s) * 4;
            float4 xv[8], wv[8];
            #pragma unroll
            for (int i = 0; i < 8; ++i)
                xv[i] = *reinterpret_cast<const float4*>(&xs[tr + 8 * i][c]);
            #pragma unroll
            for (int j = 0; j < 8; ++j)
                wv[j] = *reinterpret_cast<const float4*>(&wsh[tc + 8 * j][c]);
            #pragma unroll
            for (int i = 0; i < 8; ++i)
                #pragma unroll
                for (int j = 0; j < 8; ++j) {
                    acc[i][j] += xv[i].x * wv[j].x;
                    acc[i][j] += xv[i].y * wv[j].y;
                    acc[i][j] += xv[i].z * wv[j].z;
                    acc[i][j] += xv[i].w * wv[j].w;
                }
        }
    }

    // ---- cross-wave reduction of split-K partials (tree through LDS) ------
    __syncthreads();
    float* redA = &xs[0][0];
    float* redB = &wsh[0][0];
    if (wave == 1) {
        #pragma unroll
        for (int i = 0; i < 8; ++i)
            #pragma unroll
            for (int j = 0; j < 8; ++j)
                redA[(tr + 8 * i) * LPAD + tc + 8 * j] = acc[i][j];
    } else if (wave == 3) {
        #pragma unroll
        for (int i = 0; i < 8; ++i)
            #pragma unroll
            for (int j = 0; j < 8; ++j)
                redB[(tr + 8 * i) * LPAD + tc + 8 * j] = acc[i][j];
    }
    __syncthreads();
    if (wave == 0) {
        #pragma unroll
        for (int i = 0; i < 8; ++i)
            #pragma unroll
            for (int j = 0; j < 8; ++j)
                acc[i][j] += redA[(tr + 8 * i) * LPAD + tc + 8 * j];
    } else if (wave == 2) {
        #pragma unroll
        for (int i = 0; i < 8; ++i)
            #pragma unroll
            for (int j = 0; j < 8; ++j)
                acc[i][j] += redB[(tr + 8 * i) * LPAD + tc + 8 * j];
    }
    __syncthreads();
    if (wave == 2) {
        #pragma unroll
        for (int i = 0; i < 8; ++i)
            #pragma unroll
            for (int j = 0; j < 8; ++j)
                redA[(tr + 8 * i) * LPAD + tc + 8 * j] = acc[i][j];
    }
    __syncthreads();

    if (wave != 0) return;   // no more barriers below

    #pragma unroll
    for (int i = 0; i < 8; ++i)
        #pragma unroll
        for (int j = 0; j < 8; ++j)
            acc[i][j] += redA[(tr + 8 * i) * LPAD + tc + 8 * j];

    // ---- fused epilogue: softmax + top-2 + aux accumulation ---------------
    float auxacc[8];
    #pragma unroll
    for (int j = 0; j < 8; ++j) auxacc[j] = 0.0f;

    #pragma unroll
    for (int i = 0; i < 8; ++i) {
        // local stable top-2 over this lane's 8 experts
        float v1 = -3.4e38f, v2 = -3.4e38f;
        int   e1 = 1 << 30,  e2 = 1 << 30;
        #pragma unroll
        for (int j = 0; j < 8; ++j) {
            float v = acc[i][j];
            int   e = tc + 8 * j;
            if (v > v1 || (v == v1 && e < e1)) { v2 = v1; e2 = e1; v1 = v; e1 = e; }
            else if (v > v2 || (v == v2 && e < e2)) { v2 = v; e2 = e; }
        }
        // merge across the 8 lanes holding this row (stable, lower index wins)
        #pragma unroll
        for (int m = 1; m <= 4; m <<= 1) {
            float o1 = __shfl_xor(v1, m); int oe1 = __shfl_xor(e1, m);
            float o2 = __shfl_xor(v2, m); int oe2 = __shfl_xor(e2, m);
            bool aFirst = (v1 > o1) || (v1 == o1 && e1 < oe1);
            float n1, n2; int ne1, ne2;
            if (aFirst) {
                n1 = v1; ne1 = e1;
                bool sA = (v2 > o1) || (v2 == o1 && e2 < oe1);
                if (sA) { n2 = v2; ne2 = e2; } else { n2 = o1; ne2 = oe1; }
            } else {
                n1 = o1; ne1 = oe1;
                bool sB = (o2 > v1) || (o2 == v1 && oe2 < e1);
                if (sB) { n2 = o2; ne2 = oe2; } else { n2 = v1; ne2 = e1; }
            }
            v1 = n1; e1 = ne1; v2 = n2; e2 = ne2;
        }
        const float mx = v1;  // global row max

        float p[8];
        float sloc = 0.0f;
        #pragma unroll
        for (int j = 0; j < 8; ++j) { p[j] = expf(acc[i][j] - mx); sloc += p[j]; }
        float S = sloc;
        #pragma unroll
        for (int m = 1; m <= 4; m <<= 1) S += __shfl_xor(S, m);
        const float invS = 1.0f / S;

        const float p1 = expf(v1 - mx) * invS;   // = invS (v1 == mx)
        const float p2 = expf(v2 - mx) * invS;
        const float dn = p1 + p2 + EPSF;
        const float w1 = p1 / dn;
        const float w2 = p2 / dn;

        if (tc == 0) {
            const int r = row0 + tr + 8 * i;
            out[2 * r]                 = w1;
            out[2 * r + 1]             = w2;
            out[2 * NROWS + 2 * r]     = (float)e1;
            out[2 * NROWS + 2 * r + 1] = (float)e2;
        }
        #pragma unroll
        for (int j = 0; j < 8; ++j) auxacc[j] += p[j] * invS;
    }

    // reduce aux probs across the 8 row-groups (lanes differing in tr bits)
    #pragma unroll
    for (int m = 8; m <= 32; m <<= 1)
        #pragma unroll
        for (int j = 0; j < 8; ++j) auxacc[j] += __shfl_xor(auxacc[j], m);
    if (tr == 0) {
        #pragma unroll
        for (int j = 0; j < 8; ++j)
            atomicAdd(&meanacc[tc + 8 * j], auxacc[j]);
    }
}

__global__ void zero_ws_kernel(float* __restrict__ m)
{
    m[threadIdx.x] = 0.0f;
}

__global__ void aux_loss_kernel(const float* __restrict__ m,
                                float* __restrict__ out)
{
    const int e = threadIdx.x;           // 64 threads = 1 wave
    float mean = m[e] * (1.0f / (float)NROWS);
    float v = mean * logf(mean + EPSF);
    #pragma unroll
    for (int k = 1; k <= 32; k <<= 1) v += __shfl_xor(v, k);
    if (e == 0) out[4 * NROWS] = v;      // index 131072
}

extern "C" void kernel_launch(void* const* d_in, const int* in_sizes, int n_in,
                              void* d_out, int out_size, void* d_ws, size_t ws_size,
                              hipStream_t stream)
{
    const float* x   = (const float*)d_in[0];
    const float* gw  = (const float*)d_in[1];
    float* out       = (float*)d_out;
    float* meanacc   = (float*)d_ws;

    hipLaunchKernelGGL(zero_ws_kernel, dim3(1), dim3(NEXP), 0, stream, meanacc);
    hipLaunchKernelGGL(moe_router_kernel, dim3(NROWS / BM), dim3(256), 0, stream,
                       x, gw, out, meanacc);
    hipLaunchKernelGGL(aux_loss_kernel, dim3(1), dim3(NEXP), 0, stream,
                       meanacc, out);
}